// Round 1
// baseline (135.941 us; speedup 1.0000x reference)
//
#include <hip/hip_runtime.h>
#include <hip/hip_bf16.h>

#define S_LEN   512
#define NSTEP   511
#define CH      16
#define B_SZ    64
#define GROUPS  2
#define SIG_PG  4368     // 16 + 256 + 4096
#define SIG_TOT 8736
#define HIDDEN  256
#define OUT_CH  32
#define KCHUNKS 16
#define KLEN    546      // 8736 / 16

// ---------------------------------------------------------------------------
// Kernel 1: per-path depth-3 signature via Chen's identity.
// One block (256 threads) per path p = b*2 + g. Thread (i,j) owns c2[i,j] and
// c3[i,j,0..15]; c1[i] tracked redundantly per thread. Increments d[s][0..15]
// precomputed into LDS.
// ---------------------------------------------------------------------------
__global__ __launch_bounds__(256) void sig_kernel(
    const float* __restrict__ x,          // (64, 512, 3)
    const void*  __restrict__ lengths_raw,// (64,) int32 or int64
    const float* __restrict__ aug_w,      // (2, 12, 3)
    float* __restrict__ sig_out)          // (64, 8736)
{
    __shared__ float d[NSTEP * CH];       // 32704 B
    __shared__ float s_augw[36];

    const int p   = blockIdx.x;
    const int b   = p >> 1;
    const int g   = p & 1;
    const int tid = threadIdx.x;

    if (tid < 36) s_augw[tid] = aug_w[g * 36 + tid];

    // lengths dtype detection: all lengths >= 2, so if the second 32-bit word
    // is zero the buffer is little-endian int64 (high word), else int32.
    const int* l32 = (const int*)lengths_raw;
    const int  len = (l32[1] == 0) ? l32[2 * b] : l32[b];
    const int  lastIdx = len - 1;

    __syncthreads();

    const float* xb = x + (size_t)b * S_LEN * 3;
    for (int s = tid; s < NSTEP; s += 256) {
        float dx0 = 0.f, dx1 = 0.f, dx2 = 0.f;
        if (s < lastIdx) {                 // increments vanish once path is constant
            dx0 = xb[(s + 1) * 3 + 0] - xb[s * 3 + 0];
            dx1 = xb[(s + 1) * 3 + 1] - xb[s * 3 + 1];
            dx2 = xb[(s + 1) * 3 + 2] - xb[s * 3 + 2];
        }
        float* dp = &d[s * CH];
        dp[0] = 1.0f / 511.0f;             // time channel increment (never masked)
        dp[1] = dx0; dp[2] = dx1; dp[3] = dx2;
        #pragma unroll
        for (int e = 0; e < 12; ++e)       // aug bias cancels in increments
            dp[4 + e] = s_augw[e * 3 + 0] * dx0 +
                        s_augw[e * 3 + 1] * dx1 +
                        s_augw[e * 3 + 2] * dx2;
    }
    __syncthreads();

    const int i = tid >> 4;
    const int j = tid & 15;

    float c1i = 0.f, c2 = 0.f;
    float c3[16];
    #pragma unroll
    for (int k = 0; k < 16; ++k) c3[k] = 0.f;

    #pragma unroll 2
    for (int s = 0; s < NSTEP; ++s) {
        const float* dp = &d[s * CH];
        const float di = dp[i];
        const float dj = dp[j];
        const float4 q0 = *(const float4*)(dp + 0);
        const float4 q1 = *(const float4*)(dp + 4);
        const float4 q2 = *(const float4*)(dp + 8);
        const float4 q3 = *(const float4*)(dp + 12);

        // uses OLD c1, c2 (Chen: S <- S (x) exp(d))
        const float t   = fmaf(dj, fmaf(c1i, 0.5f, di * (1.f / 6.f)), c2);
        const float c2n = fmaf(dj, fmaf(di, 0.5f, c1i), c2);

        c3[0]  = fmaf(t, q0.x, c3[0]);  c3[1]  = fmaf(t, q0.y, c3[1]);
        c3[2]  = fmaf(t, q0.z, c3[2]);  c3[3]  = fmaf(t, q0.w, c3[3]);
        c3[4]  = fmaf(t, q1.x, c3[4]);  c3[5]  = fmaf(t, q1.y, c3[5]);
        c3[6]  = fmaf(t, q1.z, c3[6]);  c3[7]  = fmaf(t, q1.w, c3[7]);
        c3[8]  = fmaf(t, q2.x, c3[8]);  c3[9]  = fmaf(t, q2.y, c3[9]);
        c3[10] = fmaf(t, q2.z, c3[10]); c3[11] = fmaf(t, q2.w, c3[11]);
        c3[12] = fmaf(t, q3.x, c3[12]); c3[13] = fmaf(t, q3.y, c3[13]);
        c3[14] = fmaf(t, q3.z, c3[14]); c3[15] = fmaf(t, q3.w, c3[15]);

        c2  = c2n;
        c1i = c1i + di;
    }

    float* out = sig_out + (size_t)b * SIG_TOT + (size_t)g * SIG_PG;
    if (j == 0) out[i] = c1i;                       // level 1
    out[16 + i * 16 + j] = c2;                      // level 2
    float4* o3 = (float4*)(out + 272 + (size_t)(i * 16 + j) * 16);  // level 3
    o3[0] = make_float4(c3[0],  c3[1],  c3[2],  c3[3]);
    o3[1] = make_float4(c3[4],  c3[5],  c3[6],  c3[7]);
    o3[2] = make_float4(c3[8],  c3[9],  c3[10], c3[11]);
    o3[3] = make_float4(c3[12], c3[13], c3[14], c3[15]);
}

// ---------------------------------------------------------------------------
// Kernel 2a: partial sig @ w1. 256 blocks = 16 k-chunks x 16 hidden-tiles.
// Each block reads its w1 slice exactly once (w1 HBM traffic = 8.9 MB total).
// Thread t: batch bb = t>>2, quad hq = t&3 -> 4 hidden outputs (float4).
// ---------------------------------------------------------------------------
__global__ __launch_bounds__(256) void mlp1_kernel(
    const float* __restrict__ sig,   // (64, 8736)
    const float* __restrict__ w1,    // (8736, 256)
    float* __restrict__ hpart)       // (16, 64, 256)
{
    const int bx  = blockIdx.x;
    const int kc  = bx >> 4;
    const int hh  = bx & 15;
    const int tid = threadIdx.x;
    const int bb  = tid >> 2;
    const int hq  = tid & 3;
    const int hbase = hh * 16 + hq * 4;

    __shared__ float s_sig[64 * 65];   // [b][kk] padded

    float4 acc = make_float4(0.f, 0.f, 0.f, 0.f);
    const int k0 = kc * KLEN;

    for (int ks = 0; ks < KLEN; ks += 64) {
        const int klen = min(64, KLEN - ks);
        __syncthreads();
        for (int idx = tid; idx < 64 * 64; idx += 256) {
            const int rb = idx >> 6, kk = idx & 63;
            if (kk < klen)
                s_sig[rb * 65 + kk] = sig[(size_t)rb * SIG_TOT + k0 + ks + kk];
        }
        __syncthreads();
        for (int kk = 0; kk < klen; ++kk) {
            const float  sv = s_sig[bb * 65 + kk];
            const float4 wv = *(const float4*)(w1 + (size_t)(k0 + ks + kk) * HIDDEN + hbase);
            acc.x = fmaf(sv, wv.x, acc.x);
            acc.y = fmaf(sv, wv.y, acc.y);
            acc.z = fmaf(sv, wv.z, acc.z);
            acc.w = fmaf(sv, wv.w, acc.w);
        }
    }

    float4* op = (float4*)(hpart + ((size_t)(kc * 64 + bb)) * HIDDEN + hbase);
    *op = acc;
}

// ---------------------------------------------------------------------------
// Kernel 2b: reduce partials + bias + ReLU, then h @ w2 + b2.
// ---------------------------------------------------------------------------
__global__ __launch_bounds__(256) void mlp2_kernel(
    const float* __restrict__ hpart, // (16, 64, 256)
    const float* __restrict__ b1,    // (256,)
    const float* __restrict__ w2,    // (256, 32)
    const float* __restrict__ b2,    // (32,)
    float* __restrict__ outp)        // (64, 32)
{
    const int b = blockIdx.x;
    const int h = threadIdx.x;

    float acc = b1[h];
    #pragma unroll
    for (int kc = 0; kc < KCHUNKS; ++kc)
        acc += hpart[((size_t)(kc * 64 + b)) * HIDDEN + h];
    acc = fmaxf(acc, 0.f);

    __shared__ float s_h[HIDDEN];
    s_h[h] = acc;
    __syncthreads();

    if (h < OUT_CH) {
        float o = b2[h];
        #pragma unroll 8
        for (int jj = 0; jj < HIDDEN; ++jj)
            o = fmaf(s_h[jj], w2[jj * OUT_CH + h], o);
        outp[b * OUT_CH + h] = o;
    }
}

extern "C" void kernel_launch(void* const* d_in, const int* in_sizes, int n_in,
                              void* d_out, int out_size, void* d_ws, size_t ws_size,
                              hipStream_t stream) {
    const float* x       = (const float*)d_in[0];
    const void*  lengths = d_in[1];
    const float* aug_w   = (const float*)d_in[2];
    // d_in[3] = aug_b: bias cancels in path increments, unused.
    const float* w1      = (const float*)d_in[4];
    const float* b1      = (const float*)d_in[5];
    const float* w2      = (const float*)d_in[6];
    const float* b2      = (const float*)d_in[7];

    float* sig   = (float*)d_ws;                                   // 64*8736 f32 = 2,236,416 B
    float* hpart = (float*)((char*)d_ws + (size_t)B_SZ * SIG_TOT * 4); // 16*64*256 f32 = 1 MB

    sig_kernel<<<B_SZ * GROUPS, 256, 0, stream>>>(x, lengths, aug_w, sig);
    mlp1_kernel<<<256, 256, 0, stream>>>(sig, w1, hpart);
    mlp2_kernel<<<B_SZ, 256, 0, stream>>>(hpart, b1, w2, b2, (float*)d_out);
}

// Round 2
// 51.902 us; speedup vs baseline: 2.6192x; 2.6192x over previous
//
#include <hip/hip_runtime.h>
#include <hip/hip_bf16.h>

#define S_LEN   512
#define NSTEP   511
#define CH      16
#define B_SZ    64
#define SIG_PG  4368     // 16 + 256 + 4096
#define SIG_TOT 8736
#define HIDDEN  256
#define OUT_CH  32
#define NSEG    4
#define SEGLEN  128      // steps per segment (last has 127)
#define KC      128
#define KLEN    69       // ceil(8736/128)

// ---------------------------------------------------------------------------
// Phase A: signature of one 128-step segment of one path. 512 blocks =
// 128 paths x 4 segments. Thread (i,j) owns c2[i,j], c3[i,j,0..15].
// ---------------------------------------------------------------------------
__global__ __launch_bounds__(256) void seg_sig_kernel(
    const float* __restrict__ x,          // (64, 512, 3)
    const void*  __restrict__ lengths_raw,// (64,) int32 or int64
    const float* __restrict__ aug_w,      // (2, 12, 3)
    float* __restrict__ segsig)           // (512, 4368)
{
    __shared__ float d[SEGLEN * CH];      // 8 KB
    __shared__ float s_augw[36];

    const int bid  = blockIdx.x;
    const int path = bid >> 2;
    const int seg  = bid & 3;
    const int b    = path >> 1;
    const int g    = path & 1;
    const int tid  = threadIdx.x;

    if (tid < 36) s_augw[tid] = aug_w[g * 36 + tid];

    // lengths dtype detect: all lengths >= 2 -> if word1 == 0 it's int64.
    const int* l32 = (const int*)lengths_raw;
    const int  len = (l32[1] == 0) ? l32[2 * b] : l32[b];
    const int  lastIdx = len - 1;

    const int s0   = seg * SEGLEN;
    const int nloc = min(SEGLEN, NSTEP - s0);   // 128,128,128,127

    __syncthreads();

    const float* xb = x + (size_t)b * S_LEN * 3;
    for (int t = tid; t < nloc; t += 256) {
        const int s = s0 + t;
        float dx0 = 0.f, dx1 = 0.f, dx2 = 0.f;
        if (s < lastIdx) {                 // become-constant trick => dx = 0
            dx0 = xb[(s + 1) * 3 + 0] - xb[s * 3 + 0];
            dx1 = xb[(s + 1) * 3 + 1] - xb[s * 3 + 1];
            dx2 = xb[(s + 1) * 3 + 2] - xb[s * 3 + 2];
        }
        float* dp = &d[t * CH];
        dp[0] = 1.0f / 511.0f;             // time increment never masked
        dp[1] = dx0; dp[2] = dx1; dp[3] = dx2;
        #pragma unroll
        for (int e = 0; e < 12; ++e)       // aug bias cancels in increments
            dp[4 + e] = s_augw[e * 3 + 0] * dx0 +
                        s_augw[e * 3 + 1] * dx1 +
                        s_augw[e * 3 + 2] * dx2;
    }
    __syncthreads();

    const int i = tid >> 4;
    const int j = tid & 15;

    float c1i = 0.f, c2 = 0.f;
    float c3[16];
    #pragma unroll
    for (int k = 0; k < 16; ++k) c3[k] = 0.f;

    #pragma unroll 2
    for (int s = 0; s < nloc; ++s) {
        const float* dp = &d[s * CH];
        const float di = dp[i];
        const float dj = dp[j];
        const float4 q0 = *(const float4*)(dp + 0);
        const float4 q1 = *(const float4*)(dp + 4);
        const float4 q2 = *(const float4*)(dp + 8);
        const float4 q3 = *(const float4*)(dp + 12);

        const float t   = fmaf(dj, fmaf(c1i, 0.5f, di * (1.f / 6.f)), c2);
        const float c2n = fmaf(dj, fmaf(di, 0.5f, c1i), c2);

        c3[0]  = fmaf(t, q0.x, c3[0]);  c3[1]  = fmaf(t, q0.y, c3[1]);
        c3[2]  = fmaf(t, q0.z, c3[2]);  c3[3]  = fmaf(t, q0.w, c3[3]);
        c3[4]  = fmaf(t, q1.x, c3[4]);  c3[5]  = fmaf(t, q1.y, c3[5]);
        c3[6]  = fmaf(t, q1.z, c3[6]);  c3[7]  = fmaf(t, q1.w, c3[7]);
        c3[8]  = fmaf(t, q2.x, c3[8]);  c3[9]  = fmaf(t, q2.y, c3[9]);
        c3[10] = fmaf(t, q2.z, c3[10]); c3[11] = fmaf(t, q2.w, c3[11]);
        c3[12] = fmaf(t, q3.x, c3[12]); c3[13] = fmaf(t, q3.y, c3[13]);
        c3[14] = fmaf(t, q3.z, c3[14]); c3[15] = fmaf(t, q3.w, c3[15]);

        c2  = c2n;
        c1i = c1i + di;
    }

    float* out = segsig + (size_t)bid * SIG_PG;
    if (j == 0) out[i] = c1i;
    out[16 + i * 16 + j] = c2;
    float4* o3 = (float4*)(out + 272 + (size_t)(i * 16 + j) * 16);
    o3[0] = make_float4(c3[0],  c3[1],  c3[2],  c3[3]);
    o3[1] = make_float4(c3[4],  c3[5],  c3[6],  c3[7]);
    o3[2] = make_float4(c3[8],  c3[9],  c3[10], c3[11]);
    o3[3] = make_float4(c3[12], c3[13], c3[14], c3[15]);
}

// ---------------------------------------------------------------------------
// Phase B: Chen-combine the 4 segment signatures of each path.
// C1=A1+B1; C2=A2+B2+A1(x)B1; C3=A3+B3+A1(x)B2+A2(x)B1.
// ---------------------------------------------------------------------------
__global__ __launch_bounds__(256) void combine_kernel(
    const float* __restrict__ segsig,    // (512, 4368)
    float* __restrict__ sig_out)         // (64, 8736)
{
    const int path = blockIdx.x;
    const int b = path >> 1, g = path & 1;
    const int tid = threadIdx.x;
    const int i = tid >> 4, j = tid & 15;

    const float* s0 = segsig + (size_t)(path * NSEG) * SIG_PG;
    float a1i = s0[i];
    float a2  = s0[16 + i * 16 + j];
    float a3[16];
    {
        const float* r3 = s0 + 272 + (size_t)(i * 16 + j) * 16;
        #pragma unroll
        for (int q = 0; q < 4; ++q)
            *(float4*)&a3[q * 4] = *(const float4*)(r3 + q * 4);
    }

    for (int gs = 1; gs < NSEG; ++gs) {
        const float* sb = segsig + (size_t)(path * NSEG + gs) * SIG_PG;
        float b1v[16], b2r[16], b3r[16];
        #pragma unroll
        for (int q = 0; q < 4; ++q) {
            *(float4*)&b1v[q * 4] = *(const float4*)(sb + q * 4);
            *(float4*)&b2r[q * 4] = *(const float4*)(sb + 16 + j * 16 + q * 4);
            *(float4*)&b3r[q * 4] = *(const float4*)(sb + 272 + (size_t)(i * 16 + j) * 16 + q * 4);
        }
        const float b1i  = sb[i];
        const float b1j  = sb[j];
        const float b2ij = sb[16 + i * 16 + j];

        #pragma unroll
        for (int k = 0; k < 16; ++k)
            a3[k] = fmaf(a1i, b2r[k], fmaf(a2, b1v[k], a3[k] + b3r[k]));
        a2  = a2 + b2ij + a1i * b1j;
        a1i = a1i + b1i;
    }

    float* out = sig_out + (size_t)b * SIG_TOT + (size_t)g * SIG_PG;
    if (j == 0) out[i] = a1i;
    out[16 + i * 16 + j] = a2;
    float4* o3 = (float4*)(out + 272 + (size_t)(i * 16 + j) * 16);
    #pragma unroll
    for (int q = 0; q < 4; ++q)
        o3[q] = *(const float4*)&a3[q * 4];
}

// ---------------------------------------------------------------------------
// mlp1: sig(64x8736) @ w1(8736x256) partials. 512 blocks = 128 kc x 4 hh.
// Block tile: 64 batch x 64 hidden, K = 69. Wave reads 256 B contiguous w1
// per k (coalesced, each w1 element read by exactly one block); 16 FMA/load.
// ---------------------------------------------------------------------------
__global__ __launch_bounds__(256) void mlp1_kernel(
    const float* __restrict__ sig,   // (64, 8736)
    const float* __restrict__ w1,    // (8736, 256)
    float* __restrict__ hpart)       // (128, 64, 256)
{
    __shared__ float s_sig[64 * 70];   // [batch][k] padded

    const int bx  = blockIdx.x;
    const int kc  = bx >> 2;           // 0..127
    const int hh  = bx & 3;            // 0..3
    const int tid = threadIdx.x;
    const int hq  = tid & 15;          // hidden quad within 64-wide tile
    const int bg  = tid >> 4;          // batch group 0..15

    const int k0   = kc * KLEN;
    const int klen = min(KLEN, SIG_TOT - k0);   // <=0 only for kc==127 tail

    for (int idx = tid; idx < 64 * KLEN; idx += 256) {
        const int rb = idx / KLEN, kk = idx - rb * KLEN;
        if (kk < klen)
            s_sig[rb * 70 + kk] = sig[(size_t)rb * SIG_TOT + k0 + kk];
    }
    __syncthreads();

    float4 acc0 = make_float4(0.f, 0.f, 0.f, 0.f);
    float4 acc1 = acc0, acc2 = acc0, acc3 = acc0;

    const float* wp = w1 + (size_t)k0 * HIDDEN + hh * 64 + hq * 4;
    #pragma unroll 4
    for (int k = 0; k < klen; ++k) {
        const float4 wv = *(const float4*)(wp + (size_t)k * HIDDEN);
        const float sv0 = s_sig[(bg     ) * 70 + k];
        const float sv1 = s_sig[(bg + 16) * 70 + k];
        const float sv2 = s_sig[(bg + 32) * 70 + k];
        const float sv3 = s_sig[(bg + 48) * 70 + k];
        acc0.x = fmaf(sv0, wv.x, acc0.x); acc0.y = fmaf(sv0, wv.y, acc0.y);
        acc0.z = fmaf(sv0, wv.z, acc0.z); acc0.w = fmaf(sv0, wv.w, acc0.w);
        acc1.x = fmaf(sv1, wv.x, acc1.x); acc1.y = fmaf(sv1, wv.y, acc1.y);
        acc1.z = fmaf(sv1, wv.z, acc1.z); acc1.w = fmaf(sv1, wv.w, acc1.w);
        acc2.x = fmaf(sv2, wv.x, acc2.x); acc2.y = fmaf(sv2, wv.y, acc2.y);
        acc2.z = fmaf(sv2, wv.z, acc2.z); acc2.w = fmaf(sv2, wv.w, acc2.w);
        acc3.x = fmaf(sv3, wv.x, acc3.x); acc3.y = fmaf(sv3, wv.y, acc3.y);
        acc3.z = fmaf(sv3, wv.z, acc3.z); acc3.w = fmaf(sv3, wv.w, acc3.w);
    }

    const int hcol = hh * 64 + hq * 4;
    *(float4*)(hpart + ((size_t)kc * 64 + bg     ) * HIDDEN + hcol) = acc0;
    *(float4*)(hpart + ((size_t)kc * 64 + bg + 16) * HIDDEN + hcol) = acc1;
    *(float4*)(hpart + ((size_t)kc * 64 + bg + 32) * HIDDEN + hcol) = acc2;
    *(float4*)(hpart + ((size_t)kc * 64 + bg + 48) * HIDDEN + hcol) = acc3;
}

// ---------------------------------------------------------------------------
// mlp2: reduce 128 partials + bias + ReLU, then h @ w2 + b2 (8-way split).
// ---------------------------------------------------------------------------
__global__ __launch_bounds__(256) void mlp2_kernel(
    const float* __restrict__ hpart, // (128, 64, 256)
    const float* __restrict__ b1,    // (256,)
    const float* __restrict__ w2,    // (256, 32)
    const float* __restrict__ b2,    // (32,)
    float* __restrict__ outp)        // (64, 32)
{
    const int b   = blockIdx.x;
    const int tid = threadIdx.x;

    __shared__ float s_h[HIDDEN];
    __shared__ float s_p[8][33];

    float acc = b1[tid];
    #pragma unroll 8
    for (int kc = 0; kc < KC; ++kc)
        acc += hpart[((size_t)kc * 64 + b) * HIDDEN + tid];
    s_h[tid] = fmaxf(acc, 0.f);
    __syncthreads();

    const int o = tid & 31, part = tid >> 5;
    float p = 0.f;
    #pragma unroll
    for (int jj = 0; jj < 32; ++jj)
        p = fmaf(s_h[part * 32 + jj], w2[(part * 32 + jj) * OUT_CH + o], p);
    s_p[part][o] = p;
    __syncthreads();

    if (tid < OUT_CH) {
        float oacc = b2[tid];
        #pragma unroll
        for (int pp = 0; pp < 8; ++pp) oacc += s_p[pp][tid];
        outp[b * OUT_CH + tid] = oacc;
    }
}

extern "C" void kernel_launch(void* const* d_in, const int* in_sizes, int n_in,
                              void* d_out, int out_size, void* d_ws, size_t ws_size,
                              hipStream_t stream) {
    const float* x       = (const float*)d_in[0];
    const void*  lengths = d_in[1];
    const float* aug_w   = (const float*)d_in[2];
    // d_in[3] = aug_b: bias cancels in increments, unused.
    const float* w1      = (const float*)d_in[4];
    const float* b1      = (const float*)d_in[5];
    const float* w2      = (const float*)d_in[6];
    const float* b2      = (const float*)d_in[7];

    // ws layout: [0, 9 MB): segsig (phases A/B), later reused as hpart
    // (mlp1/mlp2 — segsig is dead by then). [9 MB, +2.2 MB): sig.
    float* segsig = (float*)d_ws;                       // 512*4368*4  = 8,945,664 B
    float* hpart  = (float*)d_ws;                       // 128*64*256*4 = 8,388,608 B
    float* sig    = (float*)((char*)d_ws + 9437184);    // 64*8736*4   = 2,236,416 B

    seg_sig_kernel<<<128 * NSEG, 256, 0, stream>>>(x, lengths, aug_w, segsig);
    combine_kernel<<<128, 256, 0, stream>>>(segsig, sig);
    mlp1_kernel<<<512, 256, 0, stream>>>(sig, w1, hpart);
    mlp2_kernel<<<B_SZ, 256, 0, stream>>>(hpart, b1, w2, b2, (float*)d_out);
}

// Round 3
// 34.911 us; speedup vs baseline: 3.8939x; 1.4867x over previous
//
#include <hip/hip_runtime.h>
#include <hip/hip_bf16.h>

#define S_LEN   512
#define NSTEP   511
#define B_SZ    64
#define SIG_PG  4368     // 16 + 256 + 4096
#define SIG_TOT 8736
#define HIDDEN  256
#define OUT_CH  32
#define KC      128
#define KLEN    69       // ceil(8736/128)

// ---------------------------------------------------------------------------
// Fused signature kernel. One block per batch element b (64 blocks x 1024 thr).
//
// Core idea: path increments d_s (16ch) = M_g @ u_s where u_s = [1/511, dx_s]
// (4ch) and M_g = [[1,0,0,0]; [0,I3]; [0, aug_w_g]]. So the depth-3 signature
// of the 16-ch path is the tensor-power map M^{(x)k} applied to the CORE
// signature of u (levels 4 + 16 + 64 = 84 values), which is shared by both
// groups. Steps:
//   1. stage x row -> LDS, build u[511][4] (masked by length)
//   2. 16 waves scan 32-step core segments (thread = tensor index (a,b,c))
//   3. wave 0 Chen-combines the 16 segment core sigs
//   4. expand via M_g (3 mode products) for g=0,1 and write sig (64x8736)
// ---------------------------------------------------------------------------
__global__ __launch_bounds__(1024) void sig_fused_kernel(
    const float* __restrict__ x,          // (64, 512, 3)
    const void*  __restrict__ lengths_raw,// (64,) int32 or int64
    const float* __restrict__ aug_w,      // (2, 12, 3)
    float* __restrict__ sig_out)          // (64, 8736)
{
    __shared__ alignas(16) float xs[S_LEN * 3];       // 6 KB
    __shared__ alignas(16) float u[NSTEP * 4];        // 8 KB
    __shared__ float segsig[16 * 88];                 // per-wave core sigs
    __shared__ float cs[88];                          // combined: [0,4) c1 [4,20) c2 [20,84) c3
    __shared__ alignas(16) float M[2][16][4];
    __shared__ alignas(16) float W1[2][256];          // [g][i*16 + b*4 + c]
    __shared__ alignas(16) float W2[2][1024];         // [g][i*64 + j*4 + c]
    __shared__ alignas(16) float V1[2][64];           // [g][i*4 + b]
    __shared__ float S1[2][16];

    const int b   = blockIdx.x;
    const int tid = threadIdx.x;

    // lengths dtype detect: all lengths >= 2 -> if word1 == 0 it's int64.
    const int* l32 = (const int*)lengths_raw;
    const int  len = (l32[1] == 0) ? l32[2 * b] : l32[b];
    const int  lastIdx = len - 1;

    // --- stage x, build M ---
    if (tid < 384)
        ((float4*)xs)[tid] = ((const float4*)(x + (size_t)b * S_LEN * 3))[tid];
    if (tid >= 512 && tid < 544) {
        const int t2 = tid - 512, g = t2 >> 4, row = t2 & 15;
        float4 m;
        if (row == 0)      m = make_float4(1.f, 0.f, 0.f, 0.f);
        else if (row < 4)  m = make_float4(0.f, row == 1 ? 1.f : 0.f,
                                                row == 2 ? 1.f : 0.f,
                                                row == 3 ? 1.f : 0.f);
        else {
            const float* aw = aug_w + g * 36 + (row - 4) * 3;
            m = make_float4(0.f, aw[0], aw[1], aw[2]);
        }
        *(float4*)&M[g][row][0] = m;
    }
    __syncthreads();

    // --- build u (masked increments) ---
    if (tid < NSTEP) {
        const int s = tid;
        float dx0 = 0.f, dx1 = 0.f, dx2 = 0.f;
        if (s < lastIdx) {                 // become-constant trick => dx = 0
            dx0 = xs[(s + 1) * 3 + 0] - xs[s * 3 + 0];
            dx1 = xs[(s + 1) * 3 + 1] - xs[s * 3 + 1];
            dx2 = xs[(s + 1) * 3 + 2] - xs[s * 3 + 2];
        }
        *(float4*)&u[s * 4] = make_float4(1.0f / 511.0f, dx0, dx1, dx2);
    }
    __syncthreads();

    // --- per-wave 32-step core segment scan ---
    const int wid  = tid >> 6, lane = tid & 63;
    const int a    = lane >> 4;
    const int bb   = (lane >> 2) & 3;
    const int c    = lane & 3;
    {
        const int s0   = wid * 32;
        const int nloc = min(32, NSTEP - s0);   // 32 (waves 0-14), 31 (wave 15)
        float r1 = 0.f, r2 = 0.f, r3 = 0.f;
        for (int s = s0; s < s0 + nloc; ++s) {
            const float da = u[s * 4 + a];
            const float db = u[s * 4 + bb];
            const float dc = u[s * 4 + c];
            const float t  = fmaf(db, fmaf(r1, 0.5f, da * (1.f / 6.f)), r2);
            r3 = fmaf(t, dc, r3);
            r2 = fmaf(db, fmaf(da, 0.5f, r1), r2);
            r1 += da;
        }
        segsig[wid * 88 + 20 + lane] = r3;
        if (c == 0)            segsig[wid * 88 + 4 + a * 4 + bb] = r2;
        if (bb == 0 && c == 0) segsig[wid * 88 + a]              = r1;
    }
    __syncthreads();

    // --- wave 0: serial Chen combine of 16 segments ---
    if (wid == 0) {
        float A1 = segsig[a];
        float A2 = segsig[4 + a * 4 + bb];
        float A3 = segsig[20 + lane];
        for (int sg = 1; sg < 16; ++sg) {
            const float* S = &segsig[sg * 88];
            const float B1a  = S[a];
            const float B1b  = S[bb];
            const float B1c  = S[c];
            const float B2ab = S[4 + a * 4 + bb];
            const float B2bc = S[4 + bb * 4 + c];
            const float B3   = S[20 + lane];
            A3 = fmaf(A1, B2bc, fmaf(A2, B1c, A3 + B3));  // uses OLD A1, A2
            A2 = fmaf(A1, B1b, A2 + B2ab);                // uses OLD A1
            A1 = A1 + B1a;
        }
        cs[20 + lane] = A3;
        if (c == 0)            cs[4 + a * 4 + bb] = A2;
        if (bb == 0 && c == 0) cs[a]              = A1;
    }
    __syncthreads();

    // --- expansion stage 1: W1[g][i][bc] = sum_a M[g][i][a] * C3[a][bc];
    //     V1[g][i][b] = sum_a M*C2; S1[g][i] = sum_a M*C1 ---
    if (tid < 512) {
        const int g = tid >> 8, rem = tid & 255;
        const int i = rem >> 4, bc = rem & 15;
        const float4 m = *(const float4*)&M[g][i][0];
        W1[g][rem] = fmaf(m.x, cs[20 + bc],
                     fmaf(m.y, cs[20 + 16 + bc],
                     fmaf(m.z, cs[20 + 32 + bc],
                           m.w * cs[20 + 48 + bc])));
    } else if (tid < 640) {
        const int rem = tid - 512;
        const int g = rem >> 6, r2i = rem & 63;
        const int i = r2i >> 2, bq = r2i & 3;
        const float4 m = *(const float4*)&M[g][i][0];
        V1[g][r2i] = fmaf(m.x, cs[4 + bq],
                     fmaf(m.y, cs[4 + 4 + bq],
                     fmaf(m.z, cs[4 + 8 + bq],
                           m.w * cs[4 + 12 + bq])));
    } else if (tid < 672) {
        const int rem = tid - 640;
        const int g = rem >> 4, i = rem & 15;
        const float4 m = *(const float4*)&M[g][i][0];
        S1[g][i] = fmaf(m.x, cs[0], fmaf(m.y, cs[1], fmaf(m.z, cs[2], m.w * cs[3])));
    }
    __syncthreads();

    // --- stage 2: W2[g][i][j][c] = sum_b M[g][j][b] * W1[g][i][b*4+c] ---
    #pragma unroll
    for (int rep = 0; rep < 2; ++rep) {
        const int e = tid + rep * 1024;
        const int g = e >> 10, rem = e & 1023;
        const int i = rem >> 6, j = (rem >> 2) & 15, cc = rem & 3;
        const float4 m = *(const float4*)&M[g][j][0];
        W2[g][rem] = fmaf(m.x, W1[g][i * 16 + cc],
                     fmaf(m.y, W1[g][i * 16 + 4 + cc],
                     fmaf(m.z, W1[g][i * 16 + 8 + cc],
                           m.w * W1[g][i * 16 + 12 + cc])));
    }
    __syncthreads();

    // --- stage 3: sig3[i][j][k] = sum_c M[g][k][c]*W2; sig2; sig1; write ---
    if (tid < 512) {
        const int g = tid >> 8, rem = tid & 255;
        const int i = rem >> 4, j = rem & 15;
        float* out = sig_out + (size_t)b * SIG_TOT + (size_t)g * SIG_PG;

        const float4 wv = *(const float4*)&W2[g][i * 64 + j * 4];
        float4* o3 = (float4*)(out + 272 + (size_t)(i * 16 + j) * 16);
        #pragma unroll
        for (int kq = 0; kq < 4; ++kq) {
            float4 r;
            const float4 m0 = *(const float4*)&M[g][kq * 4 + 0][0];
            const float4 m1 = *(const float4*)&M[g][kq * 4 + 1][0];
            const float4 m2 = *(const float4*)&M[g][kq * 4 + 2][0];
            const float4 m3 = *(const float4*)&M[g][kq * 4 + 3][0];
            r.x = fmaf(m0.x, wv.x, fmaf(m0.y, wv.y, fmaf(m0.z, wv.z, m0.w * wv.w)));
            r.y = fmaf(m1.x, wv.x, fmaf(m1.y, wv.y, fmaf(m1.z, wv.z, m1.w * wv.w)));
            r.z = fmaf(m2.x, wv.x, fmaf(m2.y, wv.y, fmaf(m2.z, wv.z, m2.w * wv.w)));
            r.w = fmaf(m3.x, wv.x, fmaf(m3.y, wv.y, fmaf(m3.z, wv.z, m3.w * wv.w)));
            o3[kq] = r;
        }

        const float4 v1 = *(const float4*)&V1[g][i * 4];
        const float4 mj = *(const float4*)&M[g][j][0];
        out[16 + i * 16 + j] =
            fmaf(mj.x, v1.x, fmaf(mj.y, v1.y, fmaf(mj.z, v1.z, mj.w * v1.w)));

        if (j == 0) out[i] = S1[g][i];
    }
}

// ---------------------------------------------------------------------------
// mlp1: sig(64x8736) @ w1(8736x256) partials. 512 blocks = 128 kc x 4 hh.
// Block tile: 64 batch x 64 hidden, K = 69. Wave reads 256 B contiguous w1
// per k (coalesced, each w1 element read by exactly one block); 16 FMA/load.
// ---------------------------------------------------------------------------
__global__ __launch_bounds__(256) void mlp1_kernel(
    const float* __restrict__ sig,   // (64, 8736)
    const float* __restrict__ w1,    // (8736, 256)
    float* __restrict__ hpart)       // (128, 64, 256)
{
    __shared__ float s_sig[64 * 70];   // [batch][k] padded

    const int bx  = blockIdx.x;
    const int kc  = bx >> 2;           // 0..127
    const int hh  = bx & 3;            // 0..3
    const int tid = threadIdx.x;
    const int hq  = tid & 15;          // hidden quad within 64-wide tile
    const int bg  = tid >> 4;          // batch group 0..15

    const int k0   = kc * KLEN;
    const int klen = min(KLEN, SIG_TOT - k0);   // negative only for kc==127 tail

    for (int idx = tid; idx < 64 * KLEN; idx += 256) {
        const int rb = idx / KLEN, kk = idx - rb * KLEN;
        if (kk < klen)
            s_sig[rb * 70 + kk] = sig[(size_t)rb * SIG_TOT + k0 + kk];
    }
    __syncthreads();

    float4 acc0 = make_float4(0.f, 0.f, 0.f, 0.f);
    float4 acc1 = acc0, acc2 = acc0, acc3 = acc0;

    const float* wp = w1 + (size_t)k0 * HIDDEN + hh * 64 + hq * 4;
    #pragma unroll 4
    for (int k = 0; k < klen; ++k) {
        const float4 wv = *(const float4*)(wp + (size_t)k * HIDDEN);
        const float sv0 = s_sig[(bg     ) * 70 + k];
        const float sv1 = s_sig[(bg + 16) * 70 + k];
        const float sv2 = s_sig[(bg + 32) * 70 + k];
        const float sv3 = s_sig[(bg + 48) * 70 + k];
        acc0.x = fmaf(sv0, wv.x, acc0.x); acc0.y = fmaf(sv0, wv.y, acc0.y);
        acc0.z = fmaf(sv0, wv.z, acc0.z); acc0.w = fmaf(sv0, wv.w, acc0.w);
        acc1.x = fmaf(sv1, wv.x, acc1.x); acc1.y = fmaf(sv1, wv.y, acc1.y);
        acc1.z = fmaf(sv1, wv.z, acc1.z); acc1.w = fmaf(sv1, wv.w, acc1.w);
        acc2.x = fmaf(sv2, wv.x, acc2.x); acc2.y = fmaf(sv2, wv.y, acc2.y);
        acc2.z = fmaf(sv2, wv.z, acc2.z); acc2.w = fmaf(sv2, wv.w, acc2.w);
        acc3.x = fmaf(sv3, wv.x, acc3.x); acc3.y = fmaf(sv3, wv.y, acc3.y);
        acc3.z = fmaf(sv3, wv.z, acc3.z); acc3.w = fmaf(sv3, wv.w, acc3.w);
    }

    const int hcol = hh * 64 + hq * 4;
    *(float4*)(hpart + ((size_t)kc * 64 + bg     ) * HIDDEN + hcol) = acc0;
    *(float4*)(hpart + ((size_t)kc * 64 + bg + 16) * HIDDEN + hcol) = acc1;
    *(float4*)(hpart + ((size_t)kc * 64 + bg + 32) * HIDDEN + hcol) = acc2;
    *(float4*)(hpart + ((size_t)kc * 64 + bg + 48) * HIDDEN + hcol) = acc3;
}

// ---------------------------------------------------------------------------
// mlp2: reduce 128 partials (4-way split across waves) + bias + ReLU,
// then h @ w2 + b2 (8-way split). 64 blocks x 1024 threads.
// ---------------------------------------------------------------------------
__global__ __launch_bounds__(1024) void mlp2_kernel(
    const float* __restrict__ hpart, // (128, 64, 256)
    const float* __restrict__ b1,    // (256,)
    const float* __restrict__ w2,    // (256, 32)
    const float* __restrict__ b2,    // (32,)
    float* __restrict__ outp)        // (64, 32)
{
    const int b   = blockIdx.x;
    const int tid = threadIdx.x;
    const int h   = tid & 255, q = tid >> 8;

    __shared__ float sp[4][HIDDEN];
    __shared__ float s_h[HIDDEN];
    __shared__ float s_p[8][33];

    float acc = 0.f;
    #pragma unroll 8
    for (int m = 0; m < 32; ++m) {
        const int kc = q * 32 + m;
        acc += hpart[((size_t)kc * 64 + b) * HIDDEN + h];
    }
    sp[q][h] = acc;
    __syncthreads();

    if (tid < HIDDEN) {
        const float v = b1[tid] + sp[0][tid] + sp[1][tid] + sp[2][tid] + sp[3][tid];
        s_h[tid] = fmaxf(v, 0.f);
    }
    __syncthreads();

    if (tid < 256) {
        const int o = tid & 31, part = tid >> 5;
        float p = 0.f;
        #pragma unroll
        for (int jj = 0; jj < 32; ++jj)
            p = fmaf(s_h[part * 32 + jj], w2[(part * 32 + jj) * OUT_CH + o], p);
        s_p[part][o] = p;
    }
    __syncthreads();

    if (tid < OUT_CH) {
        float oacc = b2[tid];
        #pragma unroll
        for (int pp = 0; pp < 8; ++pp) oacc += s_p[pp][tid];
        outp[b * OUT_CH + tid] = oacc;
    }
}

extern "C" void kernel_launch(void* const* d_in, const int* in_sizes, int n_in,
                              void* d_out, int out_size, void* d_ws, size_t ws_size,
                              hipStream_t stream) {
    const float* x       = (const float*)d_in[0];
    const void*  lengths = d_in[1];
    const float* aug_w   = (const float*)d_in[2];
    // d_in[3] = aug_b: bias cancels in increments, unused.
    const float* w1      = (const float*)d_in[4];
    const float* b1      = (const float*)d_in[5];
    const float* w2      = (const float*)d_in[6];
    const float* b2      = (const float*)d_in[7];

    // ws: [0, 2236416) sig; [2236416, +8 MB) hpart. (2236416 = 8736*256, aligned)
    float* sig   = (float*)d_ws;
    float* hpart = (float*)((char*)d_ws + (size_t)B_SZ * SIG_TOT * 4);

    sig_fused_kernel<<<B_SZ, 1024, 0, stream>>>(x, lengths, aug_w, sig);
    mlp1_kernel<<<512, 256, 0, stream>>>(sig, w1, hpart);
    mlp2_kernel<<<B_SZ, 1024, 0, stream>>>(hpart, b1, w2, b2, (float*)d_out);
}